// Round 8
// baseline (388.062 us; speedup 1.0000x reference)
//
#include <hip/hip_runtime.h>

// Problem constants
#define TOKENS 8192     // B*S
#define Dm 1024
#define Hm 2048
#define Sm 2048
#define D2 512
#define SLOTS 16384     // TOKENS * K
#define PADU 256        // expert segment padding unit (= gemm1 row-tile)
#define SLOTPAD (SLOTS + 8*PADU)   // 18432
#define NWE 16777216    // weight elements per array (8*2048*1024)

// Workspace layout (bytes)
#define OF_TAB 0ull                                   // float2[Sm*D2]       8 MB
#define OF_HID (OF_TAB + (size_t)Sm*D2*8)             // ushort[TOKENS*Dm]  16.8 MB
#define OF_ACT (OF_HID + (size_t)TOKENS*Dm*2)         // ushort[SLOTPAD*Hm] 75.5 MB
#define OF_W1B (OF_ACT + (size_t)SLOTPAD*Hm*2)        // ushort[NWE]        33.6 MB
#define OF_W3B (OF_W1B + (size_t)NWE*2)               // ushort[NWE]        33.6 MB
#define OF_W2B (OF_W3B + (size_t)NWE*2)               // ushort[NWE]        33.6 MB
#define OF_T2I (OF_W2B + (size_t)NWE*2)               // int[TOKENS*2]
#define OF_T2G (OF_T2I + (size_t)TOKENS*2*4)          // float[TOKENS*2]
#define OF_T2S (OF_T2G + (size_t)TOKENS*2*4)          // int[TOKENS*2]
#define OF_ST  (OF_T2S + (size_t)TOKENS*2*4)          // int[SLOTPAD]
#define OF_SG  (OF_ST + (size_t)SLOTPAD*4)            // float[SLOTPAD]
#define OF_MT  (OF_SG + (size_t)SLOTPAD*4)            // int meta[32]
#define OF_SO  (OF_MT + 1024)                         // ushort sout[SLOTPAD*Dm] 37.7 MB

// k_prep block ranges
#define PREP_TOKEN 8192
#define PREP_CONV  (PREP_TOKEN + 3 * (NWE / (256 * 8)))   // 8192 + 24576 = 32768
#define PREP_INIT  (PREP_CONV + (SLOTPAD + 255) / 256)    // + 72 = 32840

typedef __bf16 bf16x8 __attribute__((ext_vector_type(8)));
typedef short  s16x8  __attribute__((ext_vector_type(8)));
typedef float  f32x4  __attribute__((ext_vector_type(4)));

__device__ __forceinline__ unsigned short f2bf(float f) {
    union { float f; unsigned u; } v; v.f = f;
    unsigned r = v.u + 0x7fffu + ((v.u >> 16) & 1u);   // RNE
    return (unsigned short)(r >> 16);
}

__device__ __forceinline__ float bf2f(unsigned short u) {
    union { unsigned u; float f; } v; v.u = ((unsigned)u) << 16;
    return v.f;
}

__device__ __forceinline__ f32x4 mfma16(s16x8 a, s16x8 b, f32x4 c) {
    return __builtin_amdgcn_mfma_f32_16x16x32_bf16(
        __builtin_bit_cast(bf16x8, a), __builtin_bit_cast(bf16x8, b), c, 0, 0, 0);
}

// async global->LDS, 16 bytes per lane
__device__ __forceinline__ void gld16(const void* g, void* l) {
    __builtin_amdgcn_global_load_lds(
        (const __attribute__((address_space(1))) void*)g,
        (__attribute__((address_space(3))) void*)l, 16, 0, 0);
}

// XCD-chunked bijective block remap (T1). nwg must be %8==0 (it is here).
__device__ __forceinline__ int xcd_swz(int bid, int nwg) {
    int cpx = nwg >> 3;
    return (bid & 7) * cpx + (bid >> 3);
}

// ---------------- RoPE table ----------------
__global__ void k_table(float2* tab) {
    int i = blockIdx.x * 256 + threadIdx.x;   // < Sm*D2
    int s = i >> 9, j = i & 511;
    float inv = expf(-(float)j * (9.210340371976184f / 512.0f)); // 10000^(-j/512)
    float ang = (float)s * inv;
    tab[i] = make_float2(cosf(ang), sinf(ang));
}

// ---------------- fused prologue: token | weight-convert | init ------------
// Block ranges: [0,8192) token; [8192,32768) convert; [32768,32840) init.
// Convert (HBM-bound) overlaps token (latency-bound) via co-residency.
__global__ __launch_bounds__(256) void k_prep(
    const float* __restrict__ x, const float* __restrict__ nw,
    const float* __restrict__ rW, const float2* __restrict__ tab,
    const float* __restrict__ w1, const float* __restrict__ w3,
    const float* __restrict__ w2,
    unsigned short* __restrict__ hid, int* __restrict__ t2i,
    float* __restrict__ t2g,
    unsigned short* __restrict__ d1, unsigned short* __restrict__ d3,
    unsigned short* __restrict__ d2,
    int* __restrict__ slot_token, int* __restrict__ meta)
{
    __shared__ float red[4];
    __shared__ float rl[4][8];
    int bid = blockIdx.x;
    int tid = threadIdx.x;

    if (bid >= PREP_CONV) {                  // ---- init ----
        int i = (bid - PREP_CONV) * 256 + tid;
        if (i < SLOTPAD) slot_token[i] = -1;
        if (i < 8) meta[i] = 0;
        return;
    }
    if (bid >= PREP_TOKEN) {                 // ---- weight convert ----
        size_t i = ((size_t)(bid - PREP_TOKEN) * 256 + tid) * 8;
        const float* s; unsigned short* d;
        if (i < (size_t)NWE)            { s = w1; d = d1; }
        else if (i < 2ull * NWE)        { s = w3; d = d3; i -= (size_t)NWE; }
        else                            { s = w2; d = d2; i -= 2ull * NWE; }
        float4 a = *(const float4*)(s + i);
        float4 b = *(const float4*)(s + i + 4);
        s16x8 v;
        v[0]=(short)f2bf(a.x); v[1]=(short)f2bf(a.y); v[2]=(short)f2bf(a.z); v[3]=(short)f2bf(a.w);
        v[4]=(short)f2bf(b.x); v[5]=(short)f2bf(b.y); v[6]=(short)f2bf(b.z); v[7]=(short)f2bf(b.w);
        *(s16x8*)(d + i) = v;
        return;
    }

    // ---- per-token: rmsnorm + rope + router ----
    int t = bid;
    int lane = tid & 63, wid = tid >> 6;
    int s = t & (Sm - 1);
    const float* xr = x + (size_t)t * Dm;

    float v0 = xr[tid], v1 = xr[tid + 256], v2 = xr[tid + 512], v3 = xr[tid + 768];
    float ss = v0*v0 + v1*v1 + v2*v2 + v3*v3;
    #pragma unroll
    for (int o = 32; o; o >>= 1) ss += __shfl_down(ss, o);
    if (lane == 0) red[wid] = ss;
    __syncthreads();
    float tot = red[0] + red[1] + red[2] + red[3];
    float rms = rsqrtf(tot * (1.0f / Dm) + 1e-6f);

    float n0 = v0 * rms * nw[tid];
    float n1 = v1 * rms * nw[tid + 256];
    float n2 = v2 * rms * nw[tid + 512];
    float n3 = v3 * rms * nw[tid + 768];

    float2 c0 = tab[s * D2 + tid];
    float2 c1 = tab[s * D2 + tid + 256];
    float h0 = n0 * c0.x - n2 * c0.y;
    float h2 = n0 * c0.y + n2 * c0.x;
    float h1 = n1 * c1.x - n3 * c1.y;
    float h3 = n1 * c1.y + n3 * c1.x;

    size_t base = (size_t)t * Dm;
    hid[base + tid]       = f2bf(h0);
    hid[base + tid + 256] = f2bf(h1);
    hid[base + tid + 512] = f2bf(h2);
    hid[base + tid + 768] = f2bf(h3);

    float p[8];
    #pragma unroll
    for (int e = 0; e < 8; e++) {
        const float* r = rW + (size_t)e * Dm;
        p[e] = h0 * r[tid] + h1 * r[tid + 256] + h2 * r[tid + 512] + h3 * r[tid + 768];
    }
    #pragma unroll
    for (int e = 0; e < 8; e++)
        #pragma unroll
        for (int o = 32; o; o >>= 1) p[e] += __shfl_down(p[e], o);
    if (lane == 0) {
        #pragma unroll
        for (int e = 0; e < 8; e++) rl[wid][e] = p[e];
    }
    __syncthreads();
    if (tid == 0) {
        float lg[8];
        #pragma unroll
        for (int e = 0; e < 8; e++) lg[e] = rl[0][e] + rl[1][e] + rl[2][e] + rl[3][e];
        float m = lg[0];
        #pragma unroll
        for (int e = 1; e < 8; e++) m = fmaxf(m, lg[e]);
        int i0 = 0; float b0 = lg[0];
        #pragma unroll
        for (int e = 1; e < 8; e++) if (lg[e] > b0) { b0 = lg[e]; i0 = e; }
        int i1 = -1; float b1 = -3.0e38f;
        #pragma unroll
        for (int e = 0; e < 8; e++) if (e != i0 && lg[e] > b1) { b1 = lg[e]; i1 = e; }
        float p0 = expf(b0 - m), p1 = expf(b1 - m);
        float inv = 1.0f / (p0 + p1);
        t2i[2 * t] = i0; t2i[2 * t + 1] = i1;
        t2g[2 * t] = p0 * inv; t2g[2 * t + 1] = p1 * inv;
    }
}

// ---------------- expert histogram: LDS-local then 8 atomics/block ----------
__global__ __launch_bounds__(256) void k_hist(const int* __restrict__ t2i,
                                              int* __restrict__ meta) {
    __shared__ int h[8];
    int tid = threadIdx.x;
    if (tid < 8) h[tid] = 0;
    __syncthreads();
    int base = blockIdx.x * 512 + tid * 2;   // 32 blocks cover 16384 entries
    atomicAdd(&h[t2i[base]], 1);
    atomicAdd(&h[t2i[base + 1]], 1);
    __syncthreads();
    if (tid < 8) atomicAdd(&meta[tid], h[tid]);
}

// ---------------- prefix offsets (padded to PADU=256) ----------------
__global__ void k_offsets(int* meta) {
    if (threadIdx.x == 0 && blockIdx.x == 0) {
        int acc = 0;
        for (int e = 0; e < 8; e++) {
            meta[8 + e] = acc;
            acc += ((meta[e] + PADU - 1) / PADU) * PADU;
        }
        meta[16] = acc;                       // padded_total
        for (int e = 0; e < 8; e++) meta[17 + e] = meta[8 + e]; // cursors
    }
}

// ---------------- slot placement: LDS rank + 8 cursor atomics/block --------
__global__ __launch_bounds__(256) void k_place(
    const int* __restrict__ t2i, const float* __restrict__ t2g,
    int* __restrict__ slot_token, float* __restrict__ slot_gate,
    int* __restrict__ t2s, int* __restrict__ meta)
{
    __shared__ int lcnt[8];
    __shared__ int lbase[8];
    int tid = threadIdx.x;
    if (tid < 8) lcnt[tid] = 0;
    __syncthreads();
    int t = blockIdx.x * 256 + tid;
    int e0 = t2i[2 * t], e1 = t2i[2 * t + 1];
    int r0 = atomicAdd(&lcnt[e0], 1);        // LDS atomics: per-CU, fast
    int r1 = atomicAdd(&lcnt[e1], 1);
    __syncthreads();
    if (tid < 8) lbase[tid] = atomicAdd(&meta[17 + tid], lcnt[tid]);
    __syncthreads();
    int p0 = lbase[e0] + r0, p1 = lbase[e1] + r1;
    slot_token[p0] = t; slot_gate[p0] = t2g[2 * t];     t2s[2 * t]     = p0;
    slot_token[p1] = t; slot_gate[p1] = t2g[2 * t + 1]; t2s[2 * t + 1] = p1;
}

// ---------------- GEMM1: act = silu(hid@w1^T) * (hid@w3^T) ----------------
// Block = 256 slot-rows x 128 h-cols (G and U), 8 waves (2M x 4N),
// wave tile 128x32 of each of G,U. Counted-vmcnt 2-deep pipeline (T4):
// stage tile kt+1's 8 glds at top of iter kt, vmcnt(8) -> kt's loads done
// while kt+1's stay in flight across the barrier. Single COMP region.
__global__ __launch_bounds__(512, 2) void k_gemm1(
    const unsigned short* __restrict__ hid,
    const unsigned short* __restrict__ w1b, const unsigned short* __restrict__ w3b,
    const int* __restrict__ slot_token, unsigned short* __restrict__ act,
    const int* __restrict__ meta)
{
    int nwg = gridDim.x * gridDim.y;
    int bid = blockIdx.y * gridDim.x + blockIdx.x;
    int wg  = xcd_swz(bid, nwg);
    int bx  = wg % gridDim.x, by = wg / gridDim.x;

    int row0 = by * 256;
    if (row0 >= meta[16]) return;
    int e = 0;
    #pragma unroll
    for (int q = 1; q < 8; q++) if (row0 >= meta[8 + q]) e = q;
    int h0 = bx * 128;

    __shared__ unsigned short As[2][256 * 64];
    __shared__ unsigned short Bs[2][256 * 64];

    int tid = threadIdx.x, lane = tid & 63, w = tid >> 6;
    int wm = w >> 2, wn = w & 3;             // 2M x 4N
    int wrow = wm * 128, wcol = wn * 32;
    int frow = lane & 15, q4 = lane >> 4;
    int rx = frow & 7;

    // staging: granule g covers 64 rows; thread -> row g*64+(tid>>3), seg tid&7
    int grow = tid >> 3;                     // 0..63
    int sslot = (tid & 7) ^ (grow & 7);      // source k-slot (pre-swizzled)

    const unsigned short* srcA[4];
    const unsigned short* srcB[4];
    #pragma unroll
    for (int g = 0; g < 4; g++) {
        int ra = g * 64 + grow;
        int tok = slot_token[row0 + ra];  if (tok < 0) tok = 0;
        srcA[g] = hid + (size_t)tok * Dm + sslot * 8;
        int rb = g * 64 + grow;              // B rows: 0-127 w1, 128-255 w3
        srcB[g] = (rb < 128 ? w1b + ((size_t)e * Hm + h0 + rb) * Dm
                            : w3b + ((size_t)e * Hm + h0 + rb - 128) * Dm) + sslot * 8;
    }

    s16x8 a8[4][2], bG[2][2], bU[2][2];
    f32x4 accG[8][2] = {};
    f32x4 accU[8][2] = {};

#define SA(nb, g) gld16(srcA[g] + koff, (unsigned short*)&As[(nb)][(g) * 4096 + tid * 8])
#define SB(nb, g) gld16(srcB[g] + koff, (unsigned short*)&Bs[(nb)][(g) * 4096 + tid * 8])

#define RD_A(buf, half) do {                                                  \
    _Pragma("unroll") for (int i_ = 0; i_ < 4; i_++)                          \
    _Pragma("unroll") for (int kh_ = 0; kh_ < 2; kh_++) {                     \
        int sp_ = ((kh_ << 2) | q4) ^ rx;                                     \
        a8[i_][kh_] = *(const s16x8*)&As[(buf)][(wrow + (half) * 64 + i_ * 16 + frow) * 64 + sp_ * 8]; \
    } } while (0)

#define RD_B(buf, arr, base) do {                                             \
    _Pragma("unroll") for (int j_ = 0; j_ < 2; j_++)                          \
    _Pragma("unroll") for (int kh_ = 0; kh_ < 2; kh_++) {                     \
        int sp_ = ((kh_ << 2) | q4) ^ rx;                                     \
        arr[j_][kh_] = *(const s16x8*)&Bs[(buf)][((base) + wcol + j_ * 16 + frow) * 64 + sp_ * 8]; \
    } } while (0)

#define MFMA_Q(accX, bX, half) do {                                           \
    _Pragma("unroll") for (int i_ = 0; i_ < 4; i_++)                          \
    _Pragma("unroll") for (int j_ = 0; j_ < 2; j_++)                          \
    _Pragma("unroll") for (int kh_ = 0; kh_ < 2; kh_++)                       \
        accX[(half) * 4 + i_][j_] = mfma16(a8[i_][kh_], bX[j_][kh_], accX[(half) * 4 + i_][j_]); \
    } while (0)

#define COMP1(buf) do {                                                       \
    RD_A(buf, 0);                                                             \
    RD_B(buf, bG, 0);                                                         \
    MFMA_Q(accG, bG, 0);                                                      \
    RD_B(buf, bU, 128);                                                       \
    MFMA_Q(accU, bU, 0);                                                      \
    RD_A(buf, 1);                                                             \
    MFMA_Q(accG, bG, 1);                                                      \
    MFMA_Q(accU, bU, 1);                                                      \
    } while (0)

    // prologue: stage K-tile 0 into buf 0 (8 glds in flight)
    {
        int koff = 0;
        #pragma unroll
        for (int g = 0; g < 4; g++) SA(0, g);
        #pragma unroll
        for (int g = 0; g < 4; g++) SB(0, g);
    }

    for (int kt = 0; kt < 15; ++kt) {
        int buf = kt & 1, nbuf = buf ^ 1;
        {
            int koff = (kt + 1) * 64;        // stage next tile (8 glds)
            #pragma unroll
            for (int g = 0; g < 4; g++) SA(nbuf, g);
            #pragma unroll
            for (int g = 0; g < 4; g++) SB(nbuf, g);
        }
        asm volatile("s_waitcnt vmcnt(8)" ::: "memory");   // tile kt's loads done
        __builtin_amdgcn_s_barrier();
        __builtin_amdgcn_sched_barrier(0);
        COMP1(buf);
        __builtin_amdgcn_sched_barrier(0);
        __builtin_amdgcn_s_barrier();
    }
    asm volatile("s_waitcnt vmcnt(0)" ::: "memory");
    __builtin_amdgcn_s_barrier();
    __builtin_amdgcn_sched_barrier(0);
    COMP1(1);

#undef SA
#undef SB
#undef RD_A
#undef RD_B
#undef MFMA_Q
#undef COMP1

    #pragma unroll
    for (int m = 0; m < 8; m++)
        #pragma unroll
        for (int j = 0; j < 2; j++)
            #pragma unroll
            for (int r = 0; r < 4; r++) {
                int sr = row0 + wrow + m * 16 + q4 * 4 + r;
                int hc = h0 + wcol + j * 16 + frow;
                float g = accG[m][j][r], u = accU[m][j][r];
                float a = g / (1.0f + expf(-g)) * u;
                act[(size_t)sr * Hm + hc] = f2bf(a);
            }
}

// ---------------- GEMM2: sout[slot] = gate * (act @ w2^T), bf16 ----------------
// 128 rows x 128 D-cols per block; BK=64; 2-deep counted-vmcnt pipeline.
__global__ __launch_bounds__(256) void k_gemm2(
    const unsigned short* __restrict__ act, const unsigned short* __restrict__ w2b,
    const float* __restrict__ slot_gate,
    unsigned short* __restrict__ sout, const int* __restrict__ meta)
{
    int nwg = gridDim.x * gridDim.y;
    int bid = blockIdx.y * gridDim.x + blockIdx.x;
    int wg  = xcd_swz(bid, nwg);
    int bx  = wg % gridDim.x, by = wg / gridDim.x;

    int row0 = by * 128;
    if (row0 >= meta[16]) return;
    int e = 0;
    #pragma unroll
    for (int q = 1; q < 8; q++) if (row0 >= meta[8 + q]) e = q;
    int d0 = bx * 128;

    __shared__ unsigned short As[2][128 * 64];
    __shared__ unsigned short Bs[2][128 * 64];
    __shared__ float sgat[128];

    int tid = threadIdx.x, lane = tid & 63, w = tid >> 6;
    int wm = w >> 1, wn = w & 1;
    int frow = lane & 15, q4 = lane >> 4;
    int rx = frow & 7;

    if (tid < 128) sgat[tid] = slot_gate[row0 + tid];

    int r7 = (tid >> 3) & 7;
    int sslot = (tid & 7) ^ r7;

    const unsigned short* srcA[4];
    const unsigned short* srcB[4];
    #pragma unroll
    for (int i = 0; i < 4; i++) {
        int rr = i * 32 + (tid >> 3);
        srcA[i] = act + (size_t)(row0 + rr) * Hm + sslot * 8;
        srcB[i] = w2b + ((size_t)e * Dm + d0 + rr) * Hm + sslot * 8;
    }

    f32x4 acc[4][4] = {};

#define STAGE2(buf, k0) do {                                                  \
    unsigned short* la_ = &As[(buf)][tid * 8];                                \
    unsigned short* lb_ = &Bs[(buf)][tid * 8];                                \
    _Pragma("unroll")                                                         \
    for (int i_ = 0; i_ < 4; i_++) {                                          \
        gld16(srcA[i_] + (k0), la_ + i_ * 2048);                              \
        gld16(srcB[i_] + (k0), lb_ + i_ * 2048);                              \
    } } while (0)

#define COMP2(buf) do {                                                       \
    _Pragma("unroll")                                                         \
    for (int h_ = 0; h_ < 2; h_++) {                                          \
        int sp_ = ((h_ << 2) | q4) ^ rx;                                      \
        s16x8 am_[4], bn_[4];                                                 \
        _Pragma("unroll")                                                     \
        for (int i_ = 0; i_ < 4; i_++)                                        \
            am_[i_] = *(const s16x8*)&As[(buf)][(wm * 64 + i_ * 16 + frow) * 64 + sp_ * 8]; \
        _Pragma("unroll")                                                     \
        for (int j_ = 0; j_ < 4; j_++)                                        \
            bn_[j_] = *(const s16x8*)&Bs[(buf)][(wn * 64 + j_ * 16 + frow) * 64 + sp_ * 8]; \
        _Pragma("unroll")                                                     \
        for (int i_ = 0; i_ < 4; i_++)                                        \
            _Pragma("unroll")                                                 \
            for (int j_ = 0; j_ < 4; j_++)                                    \
                acc[i_][j_] = mfma16(am_[i_], bn_[j_], acc[i_][j_]);          \
    } } while (0)

    STAGE2(0, 0);
    #pragma unroll 2
    for (int kt = 0; kt < 31; ++kt) {
        STAGE2((kt + 1) & 1, (kt + 1) * 64);
        asm volatile("s_waitcnt vmcnt(8)" ::: "memory");
        __builtin_amdgcn_s_barrier();
        __builtin_amdgcn_sched_barrier(0);
        COMP2(kt & 1);
        __builtin_amdgcn_sched_barrier(0);
        __builtin_amdgcn_s_barrier();
    }
    asm volatile("s_waitcnt vmcnt(0)" ::: "memory");
    __builtin_amdgcn_s_barrier();
    __builtin_amdgcn_sched_barrier(0);
    COMP2(1);

#undef STAGE2
#undef COMP2

    #pragma unroll
    for (int i = 0; i < 4; i++) {
        #pragma unroll
        for (int r = 0; r < 4; r++) {
            int srl = wm * 64 + i * 16 + q4 * 4 + r;
            float gate = sgat[srl];
            size_t rb = (size_t)(row0 + srl) * Dm;
            #pragma unroll
            for (int j = 0; j < 4; j++) {
                int dc = d0 + wn * 64 + j * 16 + frow;
                sout[rb + dc] = f2bf(gate * acc[i][j][r]);
            }
        }
    }
}

// ---------------- final gather: out = x + sout[s0] + sout[s1] ----------------
__global__ __launch_bounds__(256) void k_final(
    const float* __restrict__ x, const unsigned short* __restrict__ sout,
    const int* __restrict__ t2s, float* __restrict__ out)
{
    int t = blockIdx.x;
    int tid = threadIdx.x;
    int s0 = t2s[2 * t], s1 = t2s[2 * t + 1];
    const float4*  xr = (const float4*)(x + (size_t)t * Dm);
    const ushort4* a  = (const ushort4*)(sout + (size_t)s0 * Dm);
    const ushort4* b  = (const ushort4*)(sout + (size_t)s1 * Dm);
    float4* o = (float4*)(out + (size_t)t * Dm);
    float4 xv = xr[tid];
    ushort4 av = a[tid], bv = b[tid];
    float4 r;
    r.x = xv.x + bf2f(av.x) + bf2f(bv.x);
    r.y = xv.y + bf2f(av.y) + bf2f(bv.y);
    r.z = xv.z + bf2f(av.z) + bf2f(bv.z);
    r.w = xv.w + bf2f(av.w) + bf2f(bv.w);
    o[tid] = r;
}

extern "C" void kernel_launch(void* const* d_in, const int* in_sizes, int n_in,
                              void* d_out, int out_size, void* d_ws, size_t ws_size,
                              hipStream_t stream) {
    const float* x  = (const float*)d_in[0];
    const float* nw = (const float*)d_in[1];
    const float* rW = (const float*)d_in[2];
    const float* w1 = (const float*)d_in[3];
    const float* w3 = (const float*)d_in[4];
    const float* w2 = (const float*)d_in[5];
    float* out = (float*)d_out;
    char* ws = (char*)d_ws;

    float2* tab = (float2*)(ws + OF_TAB);
    unsigned short* hid = (unsigned short*)(ws + OF_HID);
    unsigned short* act = (unsigned short*)(ws + OF_ACT);
    unsigned short* w1b = (unsigned short*)(ws + OF_W1B);
    unsigned short* w3b = (unsigned short*)(ws + OF_W3B);
    unsigned short* w2b = (unsigned short*)(ws + OF_W2B);
    int*   t2i  = (int*)(ws + OF_T2I);
    float* t2g  = (float*)(ws + OF_T2G);
    int*   t2s  = (int*)(ws + OF_T2S);
    int*   stok = (int*)(ws + OF_ST);
    float* sgat = (float*)(ws + OF_SG);
    int*   meta = (int*)(ws + OF_MT);
    unsigned short* sout = (unsigned short*)(ws + OF_SO);

    k_table<<<(Sm * D2) / 256, 256, 0, stream>>>(tab);
    k_prep<<<PREP_INIT, 256, 0, stream>>>(x, nw, rW, tab, w1, w3, w2,
                                          hid, t2i, t2g, w1b, w3b, w2b,
                                          stok, meta);
    k_hist<<<32, 256, 0, stream>>>(t2i, meta);
    k_offsets<<<1, 64, 0, stream>>>(meta);
    k_place<<<TOKENS / 256, 256, 0, stream>>>(t2i, t2g, stok, sgat, t2s, meta);

    dim3 g1(Hm / 128, SLOTPAD / 256);        // 16 x 72 = 1152 blocks
    k_gemm1<<<g1, 512, 0, stream>>>(hid, w1b, w3b, stok, act, meta);
    dim3 g2(Dm / 128, SLOTPAD / 128);        // 8 x 144 = 1152 blocks
    k_gemm2<<<g2, 256, 0, stream>>>(act, w2b, sgat, sout, meta);
    k_final<<<TOKENS, 256, 0, stream>>>(x, sout, t2s, out);
}

// Round 9
// 369.722 us; speedup vs baseline: 1.0496x; 1.0496x over previous
//
#include <hip/hip_runtime.h>

// Problem constants
#define TOKENS 8192     // B*S
#define Dm 1024
#define Hm 2048
#define Sm 2048
#define D2 512
#define SLOTS 16384     // TOKENS * K
#define PADU 256        // expert segment padding unit (= gemm1 row-tile)
#define SLOTPAD (SLOTS + 8*PADU)   // 18432
#define NWE 16777216    // weight elements per array (8*2048*1024)

// Workspace layout (bytes)
#define OF_TAB 0ull                                   // float2[Sm*D2]       8 MB
#define OF_HID (OF_TAB + (size_t)Sm*D2*8)             // ushort[TOKENS*Dm]  16.8 MB
#define OF_ACT (OF_HID + (size_t)TOKENS*Dm*2)         // ushort[SLOTPAD*Hm] 75.5 MB
#define OF_W1B (OF_ACT + (size_t)SLOTPAD*Hm*2)        // ushort[NWE]        33.6 MB
#define OF_W3B (OF_W1B + (size_t)NWE*2)               // ushort[NWE]        33.6 MB
#define OF_W2B (OF_W3B + (size_t)NWE*2)               // ushort[NWE]        33.6 MB
#define OF_T2I (OF_W2B + (size_t)NWE*2)               // int[TOKENS*2]
#define OF_T2G (OF_T2I + (size_t)TOKENS*2*4)          // float[TOKENS*2]
#define OF_T2S (OF_T2G + (size_t)TOKENS*2*4)          // int[TOKENS*2]
#define OF_ST  (OF_T2S + (size_t)TOKENS*2*4)          // int[SLOTPAD]
#define OF_SG  (OF_ST + (size_t)SLOTPAD*4)            // float[SLOTPAD]
#define OF_MT  (OF_SG + (size_t)SLOTPAD*4)            // int meta[32]
#define OF_SO  (OF_MT + 1024)                         // ushort sout[SLOTPAD*Dm] 37.7 MB

// k_prep block ranges
#define PREP_TOKEN 8192
#define PREP_CONV  (PREP_TOKEN + 3 * (NWE / (256 * 8)))   // 8192 + 24576 = 32768
#define PREP_INIT  (PREP_CONV + (SLOTPAD + 255) / 256)    // + 72 = 32840

typedef __bf16 bf16x8 __attribute__((ext_vector_type(8)));
typedef short  s16x8  __attribute__((ext_vector_type(8)));
typedef float  f32x4  __attribute__((ext_vector_type(4)));

__device__ __forceinline__ unsigned short f2bf(float f) {
    union { float f; unsigned u; } v; v.f = f;
    unsigned r = v.u + 0x7fffu + ((v.u >> 16) & 1u);   // RNE
    return (unsigned short)(r >> 16);
}

__device__ __forceinline__ float bf2f(unsigned short u) {
    union { unsigned u; float f; } v; v.u = ((unsigned)u) << 16;
    return v.f;
}

__device__ __forceinline__ f32x4 mfma16(s16x8 a, s16x8 b, f32x4 c) {
    return __builtin_amdgcn_mfma_f32_16x16x32_bf16(
        __builtin_bit_cast(bf16x8, a), __builtin_bit_cast(bf16x8, b), c, 0, 0, 0);
}

// async global->LDS, 16 bytes per lane
__device__ __forceinline__ void gld16(const void* g, void* l) {
    __builtin_amdgcn_global_load_lds(
        (const __attribute__((address_space(1))) void*)g,
        (__attribute__((address_space(3))) void*)l, 16, 0, 0);
}

// XCD-chunked bijective block remap (T1). nwg must be %8==0 (it is here).
__device__ __forceinline__ int xcd_swz(int bid, int nwg) {
    int cpx = nwg >> 3;
    return (bid & 7) * cpx + (bid >> 3);
}

// ---------------- RoPE table ----------------
__global__ void k_table(float2* tab) {
    int i = blockIdx.x * 256 + threadIdx.x;   // < Sm*D2
    int s = i >> 9, j = i & 511;
    float inv = expf(-(float)j * (9.210340371976184f / 512.0f)); // 10000^(-j/512)
    float ang = (float)s * inv;
    tab[i] = make_float2(cosf(ang), sinf(ang));
}

// ---------------- fused prologue: token | weight-convert | init ------------
__global__ __launch_bounds__(256) void k_prep(
    const float* __restrict__ x, const float* __restrict__ nw,
    const float* __restrict__ rW, const float2* __restrict__ tab,
    const float* __restrict__ w1, const float* __restrict__ w3,
    const float* __restrict__ w2,
    unsigned short* __restrict__ hid, int* __restrict__ t2i,
    float* __restrict__ t2g,
    unsigned short* __restrict__ d1, unsigned short* __restrict__ d3,
    unsigned short* __restrict__ d2,
    int* __restrict__ slot_token, int* __restrict__ meta)
{
    __shared__ float red[4];
    __shared__ float rl[4][8];
    int bid = blockIdx.x;
    int tid = threadIdx.x;

    if (bid >= PREP_CONV) {                  // ---- init ----
        int i = (bid - PREP_CONV) * 256 + tid;
        if (i < SLOTPAD) slot_token[i] = -1;
        if (i < 8) meta[i] = 0;
        return;
    }
    if (bid >= PREP_TOKEN) {                 // ---- weight convert ----
        size_t i = ((size_t)(bid - PREP_TOKEN) * 256 + tid) * 8;
        const float* s; unsigned short* d;
        if (i < (size_t)NWE)            { s = w1; d = d1; }
        else if (i < 2ull * NWE)        { s = w3; d = d3; i -= (size_t)NWE; }
        else                            { s = w2; d = d2; i -= 2ull * NWE; }
        float4 a = *(const float4*)(s + i);
        float4 b = *(const float4*)(s + i + 4);
        s16x8 v;
        v[0]=(short)f2bf(a.x); v[1]=(short)f2bf(a.y); v[2]=(short)f2bf(a.z); v[3]=(short)f2bf(a.w);
        v[4]=(short)f2bf(b.x); v[5]=(short)f2bf(b.y); v[6]=(short)f2bf(b.z); v[7]=(short)f2bf(b.w);
        *(s16x8*)(d + i) = v;
        return;
    }

    // ---- per-token: rmsnorm + rope + router ----
    int t = bid;
    int lane = tid & 63, wid = tid >> 6;
    int s = t & (Sm - 1);
    const float* xr = x + (size_t)t * Dm;

    float v0 = xr[tid], v1 = xr[tid + 256], v2 = xr[tid + 512], v3 = xr[tid + 768];
    float ss = v0*v0 + v1*v1 + v2*v2 + v3*v3;
    #pragma unroll
    for (int o = 32; o; o >>= 1) ss += __shfl_down(ss, o);
    if (lane == 0) red[wid] = ss;
    __syncthreads();
    float tot = red[0] + red[1] + red[2] + red[3];
    float rms = rsqrtf(tot * (1.0f / Dm) + 1e-6f);

    float n0 = v0 * rms * nw[tid];
    float n1 = v1 * rms * nw[tid + 256];
    float n2 = v2 * rms * nw[tid + 512];
    float n3 = v3 * rms * nw[tid + 768];

    float2 c0 = tab[s * D2 + tid];
    float2 c1 = tab[s * D2 + tid + 256];
    float h0 = n0 * c0.x - n2 * c0.y;
    float h2 = n0 * c0.y + n2 * c0.x;
    float h1 = n1 * c1.x - n3 * c1.y;
    float h3 = n1 * c1.y + n3 * c1.x;

    size_t base = (size_t)t * Dm;
    hid[base + tid]       = f2bf(h0);
    hid[base + tid + 256] = f2bf(h1);
    hid[base + tid + 512] = f2bf(h2);
    hid[base + tid + 768] = f2bf(h3);

    float p[8];
    #pragma unroll
    for (int e = 0; e < 8; e++) {
        const float* r = rW + (size_t)e * Dm;
        p[e] = h0 * r[tid] + h1 * r[tid + 256] + h2 * r[tid + 512] + h3 * r[tid + 768];
    }
    #pragma unroll
    for (int e = 0; e < 8; e++)
        #pragma unroll
        for (int o = 32; o; o >>= 1) p[e] += __shfl_down(p[e], o);
    if (lane == 0) {
        #pragma unroll
        for (int e = 0; e < 8; e++) rl[wid][e] = p[e];
    }
    __syncthreads();
    if (tid == 0) {
        float lg[8];
        #pragma unroll
        for (int e = 0; e < 8; e++) lg[e] = rl[0][e] + rl[1][e] + rl[2][e] + rl[3][e];
        float m = lg[0];
        #pragma unroll
        for (int e = 1; e < 8; e++) m = fmaxf(m, lg[e]);
        int i0 = 0; float b0 = lg[0];
        #pragma unroll
        for (int e = 1; e < 8; e++) if (lg[e] > b0) { b0 = lg[e]; i0 = e; }
        int i1 = -1; float b1 = -3.0e38f;
        #pragma unroll
        for (int e = 0; e < 8; e++) if (e != i0 && lg[e] > b1) { b1 = lg[e]; i1 = e; }
        float p0 = expf(b0 - m), p1 = expf(b1 - m);
        float inv = 1.0f / (p0 + p1);
        t2i[2 * t] = i0; t2i[2 * t + 1] = i1;
        t2g[2 * t] = p0 * inv; t2g[2 * t + 1] = p1 * inv;
    }
}

// ---------------- expert histogram: LDS-local then 8 atomics/block ----------
__global__ __launch_bounds__(256) void k_hist(const int* __restrict__ t2i,
                                              int* __restrict__ meta) {
    __shared__ int h[8];
    int tid = threadIdx.x;
    if (tid < 8) h[tid] = 0;
    __syncthreads();
    int base = blockIdx.x * 512 + tid * 2;   // 32 blocks cover 16384 entries
    atomicAdd(&h[t2i[base]], 1);
    atomicAdd(&h[t2i[base + 1]], 1);
    __syncthreads();
    if (tid < 8) atomicAdd(&meta[tid], h[tid]);
}

// ---------------- prefix offsets (padded to PADU=256) ----------------
__global__ void k_offsets(int* meta) {
    if (threadIdx.x == 0 && blockIdx.x == 0) {
        int acc = 0;
        for (int e = 0; e < 8; e++) {
            meta[8 + e] = acc;
            acc += ((meta[e] + PADU - 1) / PADU) * PADU;
        }
        meta[16] = acc;                       // padded_total
        for (int e = 0; e < 8; e++) meta[17 + e] = meta[8 + e]; // cursors
    }
}

// ---------------- slot placement: LDS rank + 8 cursor atomics/block --------
__global__ __launch_bounds__(256) void k_place(
    const int* __restrict__ t2i, const float* __restrict__ t2g,
    int* __restrict__ slot_token, float* __restrict__ slot_gate,
    int* __restrict__ t2s, int* __restrict__ meta)
{
    __shared__ int lcnt[8];
    __shared__ int lbase[8];
    int tid = threadIdx.x;
    if (tid < 8) lcnt[tid] = 0;
    __syncthreads();
    int t = blockIdx.x * 256 + tid;
    int e0 = t2i[2 * t], e1 = t2i[2 * t + 1];
    int r0 = atomicAdd(&lcnt[e0], 1);        // LDS atomics: per-CU, fast
    int r1 = atomicAdd(&lcnt[e1], 1);
    __syncthreads();
    if (tid < 8) lbase[tid] = atomicAdd(&meta[17 + tid], lcnt[tid]);
    __syncthreads();
    int p0 = lbase[e0] + r0, p1 = lbase[e1] + r1;
    slot_token[p0] = t; slot_gate[p0] = t2g[2 * t];     t2s[2 * t]     = p0;
    slot_token[p1] = t; slot_gate[p1] = t2g[2 * t + 1]; t2s[2 * t + 1] = p1;
}

// ---------------- GEMM1: act = silu(hid@w1^T) * (hid@w3^T) ----------------
// 256 slot-rows x 128 h-cols (G and U), 8 waves (2M x 4N), 4 phases/K-tile.
// r7 phase interleave + T4 counted vmcnt. Granules (64 rows each):
// A0..A3 = slot rows, B0,B1 = w1 rows 0-127, B2,B3 = w3 rows 128-255.
// Need-order staging: P0 {A0,A2,B0,B1}, P1 {B2,B3}, P2 {A1,A3}.
// Waits: P0-close vmcnt(6), P1-close vmcnt(6), P3-close vmcnt(4). Never 0.
__global__ __launch_bounds__(512) void k_gemm1(
    const unsigned short* __restrict__ hid,
    const unsigned short* __restrict__ w1b, const unsigned short* __restrict__ w3b,
    const int* __restrict__ slot_token, unsigned short* __restrict__ act,
    const int* __restrict__ meta)
{
    int nwg = gridDim.x * gridDim.y;
    int bid = blockIdx.y * gridDim.x + blockIdx.x;
    int wg  = xcd_swz(bid, nwg);
    int bx  = wg % gridDim.x, by = wg / gridDim.x;

    int row0 = by * 256;
    if (row0 >= meta[16]) return;
    int e = 0;
    #pragma unroll
    for (int q = 1; q < 8; q++) if (row0 >= meta[8 + q]) e = q;
    int h0 = bx * 128;

    __shared__ unsigned short As[2][256 * 64];
    __shared__ unsigned short Bs[2][256 * 64];

    int tid = threadIdx.x, lane = tid & 63, w = tid >> 6;
    int wm = w >> 2, wn = w & 3;             // 2M x 4N
    int wrow = wm * 128, wcol = wn * 32;
    int frow = lane & 15, q4 = lane >> 4;
    int rx = frow & 7;

    int grow = tid >> 3;                     // 0..63
    int sslot = (tid & 7) ^ (grow & 7);      // source k-slot (pre-swizzled)

    const unsigned short* srcA[4];
    const unsigned short* srcB[4];
    #pragma unroll
    for (int g = 0; g < 4; g++) {
        int ra = g * 64 + grow;
        int tok = slot_token[row0 + ra];  if (tok < 0) tok = 0;
        srcA[g] = hid + (size_t)tok * Dm + sslot * 8;
        int rb = g * 64 + grow;              // B rows: 0-127 w1, 128-255 w3
        srcB[g] = (rb < 128 ? w1b + ((size_t)e * Hm + h0 + rb) * Dm
                            : w3b + ((size_t)e * Hm + h0 + rb - 128) * Dm) + sslot * 8;
    }

    s16x8 a8[4][2], bG[2][2], bU[2][2];
    f32x4 accG[8][2] = {};
    f32x4 accU[8][2] = {};

#define SA(nb, g) gld16(srcA[g] + koff, (unsigned short*)&As[(nb)][(g) * 4096 + tid * 8])
#define SB(nb, g) gld16(srcB[g] + koff, (unsigned short*)&Bs[(nb)][(g) * 4096 + tid * 8])

#define RD_A(buf, half) do {                                                  \
    _Pragma("unroll") for (int i_ = 0; i_ < 4; i_++)                          \
    _Pragma("unroll") for (int kh_ = 0; kh_ < 2; kh_++) {                     \
        int sp_ = ((kh_ << 2) | q4) ^ rx;                                     \
        a8[i_][kh_] = *(const s16x8*)&As[(buf)][(wrow + (half) * 64 + i_ * 16 + frow) * 64 + sp_ * 8]; \
    } } while (0)

#define RD_B(buf, arr, base) do {                                             \
    _Pragma("unroll") for (int j_ = 0; j_ < 2; j_++)                          \
    _Pragma("unroll") for (int kh_ = 0; kh_ < 2; kh_++) {                     \
        int sp_ = ((kh_ << 2) | q4) ^ rx;                                     \
        arr[j_][kh_] = *(const s16x8*)&Bs[(buf)][((base) + wcol + j_ * 16 + frow) * 64 + sp_ * 8]; \
    } } while (0)

#define MFMA_Q(accX, bX, half) do {                                           \
    _Pragma("unroll") for (int i_ = 0; i_ < 4; i_++)                          \
    _Pragma("unroll") for (int j_ = 0; j_ < 2; j_++)                          \
    _Pragma("unroll") for (int kh_ = 0; kh_ < 2; kh_++)                       \
        accX[(half) * 4 + i_][j_] = mfma16(a8[i_][kh_], bX[j_][kh_], accX[(half) * 4 + i_][j_]); \
    } while (0)

#define PH_PRE  do { __builtin_amdgcn_s_barrier();                            \
    asm volatile("s_waitcnt lgkmcnt(0)" ::: "memory");                        \
    __builtin_amdgcn_sched_barrier(0);                                        \
    __builtin_amdgcn_s_setprio(1); } while (0)
#define PH_CLOSE(N) do { __builtin_amdgcn_s_setprio(0);                       \
    asm volatile("s_waitcnt vmcnt(" #N ")" ::: "memory");                     \
    __builtin_amdgcn_s_barrier(); } while (0)
#define PH_CLOSE_NW do { __builtin_amdgcn_s_setprio(0);                       \
    __builtin_amdgcn_s_barrier(); } while (0)

    // prologue: stage K-tile 0 into buf 0 in need-order
    {
        int koff = 0;
        SA(0, 0); SA(0, 2); SB(0, 0); SB(0, 1);
        SB(0, 2); SB(0, 3); SA(0, 1); SA(0, 3);
    }
    asm volatile("s_waitcnt vmcnt(4)" ::: "memory");   // A0,A2,B0,B1 landed
    __builtin_amdgcn_s_barrier();

    for (int kt = 0; kt < 15; ++kt) {
        int buf = kt & 1, nbuf = buf ^ 1;
        int koff = (kt + 1) * 64;
        // P0: uses A0,A2 + B0,B1; stages next {A0,A2,B0,B1}
        RD_A(buf, 0); RD_B(buf, bG, 0);
        SA(nbuf, 0); SA(nbuf, 2); SB(nbuf, 0); SB(nbuf, 1);
        PH_PRE; MFMA_Q(accG, bG, 0); PH_CLOSE(6);      // prev B2,B3 done
        // P1: uses B2,B3; stages next {B2,B3}
        RD_B(buf, bU, 128);
        SB(nbuf, 2); SB(nbuf, 3);
        PH_PRE; MFMA_Q(accU, bU, 0); PH_CLOSE(6);      // prev A1,A3 done
        // P2: uses A1,A3; stages next {A1,A3}
        RD_A(buf, 1);
        SA(nbuf, 1); SA(nbuf, 3);
        PH_PRE; MFMA_Q(accG, bG, 1); PH_CLOSE_NW;
        // P3: register-only
        __builtin_amdgcn_s_setprio(1);
        MFMA_Q(accU, bU, 1);
        PH_CLOSE(4);                                   // next A0,A2,B0,B1 done
        __builtin_amdgcn_sched_barrier(0);
    }

    // tail: K-tile 15 from buf 1; in-flight <=4 {B2,B3,A1,A3}
    RD_A(1, 0); RD_B(1, bG, 0);
    PH_PRE; MFMA_Q(accG, bG, 0); PH_CLOSE(2);          // B2,B3 done
    RD_B(1, bU, 128);
    PH_PRE; MFMA_Q(accU, bU, 0); PH_CLOSE(0);          // A1,A3 done
    RD_A(1, 1);
    PH_PRE; MFMA_Q(accG, bG, 1); PH_CLOSE_NW;
    __builtin_amdgcn_s_setprio(1);
    MFMA_Q(accU, bU, 1);
    __builtin_amdgcn_s_setprio(0);

#undef SA
#undef SB
#undef RD_A
#undef RD_B
#undef MFMA_Q
#undef PH_PRE
#undef PH_CLOSE
#undef PH_CLOSE_NW

    #pragma unroll
    for (int m = 0; m < 8; m++)
        #pragma unroll
        for (int j = 0; j < 2; j++)
            #pragma unroll
            for (int r = 0; r < 4; r++) {
                int sr = row0 + wrow + m * 16 + q4 * 4 + r;
                int hc = h0 + wcol + j * 16 + frow;
                float g = accG[m][j][r], u = accU[m][j][r];
                float a = g / (1.0f + expf(-g)) * u;
                act[(size_t)sr * Hm + hc] = f2bf(a);
            }
}

// ---------------- GEMM2: sout[slot] = gate * (act @ w2^T), bf16 ----------------
// 128 rows x 128 D-cols per block; BK=64; 2-deep counted-vmcnt pipeline.
__global__ __launch_bounds__(256) void k_gemm2(
    const unsigned short* __restrict__ act, const unsigned short* __restrict__ w2b,
    const float* __restrict__ slot_gate,
    unsigned short* __restrict__ sout, const int* __restrict__ meta)
{
    int nwg = gridDim.x * gridDim.y;
    int bid = blockIdx.y * gridDim.x + blockIdx.x;
    int wg  = xcd_swz(bid, nwg);
    int bx  = wg % gridDim.x, by = wg / gridDim.x;

    int row0 = by * 128;
    if (row0 >= meta[16]) return;
    int e = 0;
    #pragma unroll
    for (int q = 1; q < 8; q++) if (row0 >= meta[8 + q]) e = q;
    int d0 = bx * 128;

    __shared__ unsigned short As[2][128 * 64];
    __shared__ unsigned short Bs[2][128 * 64];
    __shared__ float sgat[128];

    int tid = threadIdx.x, lane = tid & 63, w = tid >> 6;
    int wm = w >> 1, wn = w & 1;
    int frow = lane & 15, q4 = lane >> 4;
    int rx = frow & 7;

    if (tid < 128) sgat[tid] = slot_gate[row0 + tid];

    int r7 = (tid >> 3) & 7;
    int sslot = (tid & 7) ^ r7;

    const unsigned short* srcA[4];
    const unsigned short* srcB[4];
    #pragma unroll
    for (int i = 0; i < 4; i++) {
        int rr = i * 32 + (tid >> 3);
        srcA[i] = act + (size_t)(row0 + rr) * Hm + sslot * 8;
        srcB[i] = w2b + ((size_t)e * Dm + d0 + rr) * Hm + sslot * 8;
    }

    f32x4 acc[4][4] = {};

#define STAGE2(buf, k0) do {                                                  \
    unsigned short* la_ = &As[(buf)][tid * 8];                                \
    unsigned short* lb_ = &Bs[(buf)][tid * 8];                                \
    _Pragma("unroll")                                                         \
    for (int i_ = 0; i_ < 4; i_++) {                                          \
        gld16(srcA[i_] + (k0), la_ + i_ * 2048);                              \
        gld16(srcB[i_] + (k0), lb_ + i_ * 2048);                              \
    } } while (0)

#define COMP2(buf) do {                                                       \
    _Pragma("unroll")                                                         \
    for (int h_ = 0; h_ < 2; h_++) {                                          \
        int sp_ = ((h_ << 2) | q4) ^ rx;                                      \
        s16x8 am_[4], bn_[4];                                                 \
        _Pragma("unroll")                                                     \
        for (int i_ = 0; i_ < 4; i_++)                                        \
            am_[i_] = *(const s16x8*)&As[(buf)][(wm * 64 + i_ * 16 + frow) * 64 + sp_ * 8]; \
        _Pragma("unroll")                                                     \
        for (int j_ = 0; j_ < 4; j_++)                                        \
            bn_[j_] = *(const s16x8*)&Bs[(buf)][(wn * 64 + j_ * 16 + frow) * 64 + sp_ * 8]; \
        _Pragma("unroll")                                                     \
        for (int i_ = 0; i_ < 4; i_++)                                        \
            _Pragma("unroll")                                                 \
            for (int j_ = 0; j_ < 4; j_++)                                    \
                acc[i_][j_] = mfma16(am_[i_], bn_[j_], acc[i_][j_]);          \
    } } while (0)

    STAGE2(0, 0);
    #pragma unroll 2
    for (int kt = 0; kt < 31; ++kt) {
        STAGE2((kt + 1) & 1, (kt + 1) * 64);
        asm volatile("s_waitcnt vmcnt(8)" ::: "memory");
        __builtin_amdgcn_s_barrier();
        __builtin_amdgcn_sched_barrier(0);
        COMP2(kt & 1);
        __builtin_amdgcn_sched_barrier(0);
        __builtin_amdgcn_s_barrier();
    }
    asm volatile("s_waitcnt vmcnt(0)" ::: "memory");
    __builtin_amdgcn_s_barrier();
    __builtin_amdgcn_sched_barrier(0);
    COMP2(1);

#undef STAGE2
#undef COMP2

    #pragma unroll
    for (int i = 0; i < 4; i++) {
        #pragma unroll
        for (int r = 0; r < 4; r++) {
            int srl = wm * 64 + i * 16 + q4 * 4 + r;
            float gate = sgat[srl];
            size_t rb = (size_t)(row0 + srl) * Dm;
            #pragma unroll
            for (int j = 0; j < 4; j++) {
                int dc = d0 + wn * 64 + j * 16 + frow;
                sout[rb + dc] = f2bf(gate * acc[i][j][r]);
            }
        }
    }
}

// ---------------- final gather: out = x + sout[s0] + sout[s1] ----------------
__global__ __launch_bounds__(256) void k_final(
    const float* __restrict__ x, const unsigned short* __restrict__ sout,
    const int* __restrict__ t2s, float* __restrict__ out)
{
    int t = blockIdx.x;
    int tid = threadIdx.x;
    int s0 = t2s[2 * t], s1 = t2s[2 * t + 1];
    const float4*  xr = (const float4*)(x + (size_t)t * Dm);
    const ushort4* a  = (const ushort4*)(sout + (size_t)s0 * Dm);
    const ushort4* b  = (const ushort4*)(sout + (size_t)s1 * Dm);
    float4* o = (float4*)(out + (size_t)t * Dm);
    float4 xv = xr[tid];
    ushort4 av = a[tid], bv = b[tid];
    float4 r;
    r.x = xv.x + bf2f(av.x) + bf2f(bv.x);
    r.y = xv.y + bf2f(av.y) + bf2f(bv.y);
    r.z = xv.z + bf2f(av.z) + bf2f(bv.z);
    r.w = xv.w + bf2f(av.w) + bf2f(bv.w);
    o[tid] = r;
}

extern "C" void kernel_launch(void* const* d_in, const int* in_sizes, int n_in,
                              void* d_out, int out_size, void* d_ws, size_t ws_size,
                              hipStream_t stream) {
    const float* x  = (const float*)d_in[0];
    const float* nw = (const float*)d_in[1];
    const float* rW = (const float*)d_in[2];
    const float* w1 = (const float*)d_in[3];
    const float* w3 = (const float*)d_in[4];
    const float* w2 = (const float*)d_in[5];
    float* out = (float*)d_out;
    char* ws = (char*)d_ws;

    float2* tab = (float2*)(ws + OF_TAB);
    unsigned short* hid = (unsigned short*)(ws + OF_HID);
    unsigned short* act = (unsigned short*)(ws + OF_ACT);
    unsigned short* w1b = (unsigned short*)(ws + OF_W1B);
    unsigned short* w3b = (unsigned short*)(ws + OF_W3B);
    unsigned short* w2b = (unsigned short*)(ws + OF_W2B);
    int*   t2i  = (int*)(ws + OF_T2I);
    float* t2g  = (float*)(ws + OF_T2G);
    int*   t2s  = (int*)(ws + OF_T2S);
    int*   stok = (int*)(ws + OF_ST);
    float* sgat = (float*)(ws + OF_SG);
    int*   meta = (int*)(ws + OF_MT);
    unsigned short* sout = (unsigned short*)(ws + OF_SO);

    k_table<<<(Sm * D2) / 256, 256, 0, stream>>>(tab);
    k_prep<<<PREP_INIT, 256, 0, stream>>>(x, nw, rW, tab, w1, w3, w2,
                                          hid, t2i, t2g, w1b, w3b, w2b,
                                          stok, meta);
    k_hist<<<32, 256, 0, stream>>>(t2i, meta);
    k_offsets<<<1, 64, 0, stream>>>(meta);
    k_place<<<TOKENS / 256, 256, 0, stream>>>(t2i, t2g, stok, sgat, t2s, meta);

    dim3 g1(Hm / 128, SLOTPAD / 256);        // 16 x 72 = 1152 blocks
    k_gemm1<<<g1, 512, 0, stream>>>(hid, w1b, w3b, stok, act, meta);
    dim3 g2(Dm / 128, SLOTPAD / 128);        // 8 x 144 = 1152 blocks
    k_gemm2<<<g2, 256, 0, stream>>>(act, w2b, sgat, sout, meta);
    k_final<<<TOKENS, 256, 0, stream>>>(x, sout, t2s, out);
}

// Round 10
// 366.663 us; speedup vs baseline: 1.0584x; 1.0083x over previous
//
#include <hip/hip_runtime.h>

// Problem constants
#define TOKENS 8192     // B*S
#define Dm 1024
#define Hm 2048
#define Sm 2048
#define D2 512
#define SLOTS 16384     // TOKENS * K
#define PADU 128        // expert segment padding unit (= GEMM row-tile)
#define SLOTPAD (SLOTS + 8*PADU)   // 17408
#define NWE 16777216    // weight elements per array (8*2048*1024)

// Workspace layout (bytes)
#define OF_TAB 0ull                                   // (unused, reserved)
#define OF_HID (OF_TAB + (size_t)Sm*D2*8)             // ushort[TOKENS*Dm]
#define OF_ACT (OF_HID + (size_t)TOKENS*Dm*2)         // ushort[SLOTPAD*Hm]
#define OF_W1B (OF_ACT + (size_t)SLOTPAD*Hm*2)        // ushort[NWE]
#define OF_W3B (OF_W1B + (size_t)NWE*2)               // ushort[NWE]
#define OF_W2B (OF_W3B + (size_t)NWE*2)               // ushort[NWE]
#define OF_T2I (OF_W2B + (size_t)NWE*2)               // int[TOKENS*2]
#define OF_T2G (OF_T2I + (size_t)TOKENS*2*4)          // float[TOKENS*2]
#define OF_T2S (OF_T2G + (size_t)TOKENS*2*4)          // int[TOKENS*2]
#define OF_ST  (OF_T2S + (size_t)TOKENS*2*4)          // int[SLOTPAD]
#define OF_SG  (OF_ST + (size_t)SLOTPAD*4)            // float[SLOTPAD]
#define OF_MT  (OF_SG + (size_t)SLOTPAD*4)            // int meta[32]
#define OF_SO  (OF_MT + 1024)                         // ushort sout[SLOTPAD*Dm]

// k_prep block ranges
#define PREP_TOKEN 8192
#define PREP_CONV  (PREP_TOKEN + 3 * (NWE / (256 * 8)))   // 32768
#define PREP_INIT  (PREP_CONV + (SLOTPAD + 255) / 256)    // + 68 = 32836

typedef __bf16 bf16x8 __attribute__((ext_vector_type(8)));
typedef short  s16x8  __attribute__((ext_vector_type(8)));
typedef float  f32x4  __attribute__((ext_vector_type(4)));

__device__ __forceinline__ unsigned short f2bf(float f) {
    union { float f; unsigned u; } v; v.f = f;
    unsigned r = v.u + 0x7fffu + ((v.u >> 16) & 1u);   // RNE
    return (unsigned short)(r >> 16);
}

__device__ __forceinline__ float bf2f(unsigned short u) {
    union { unsigned u; float f; } v; v.u = ((unsigned)u) << 16;
    return v.f;
}

__device__ __forceinline__ f32x4 mfma16(s16x8 a, s16x8 b, f32x4 c) {
    return __builtin_amdgcn_mfma_f32_16x16x32_bf16(
        __builtin_bit_cast(bf16x8, a), __builtin_bit_cast(bf16x8, b), c, 0, 0, 0);
}

// async global->LDS, 16 bytes per lane
__device__ __forceinline__ void gld16(const void* g, void* l) {
    __builtin_amdgcn_global_load_lds(
        (const __attribute__((address_space(1))) void*)g,
        (__attribute__((address_space(3))) void*)l, 16, 0, 0);
}

// XCD-chunked bijective block remap (T1). nwg must be %8==0 (it is here).
__device__ __forceinline__ int xcd_swz(int bid, int nwg) {
    int cpx = nwg >> 3;
    return (bid & 7) * cpx + (bid >> 3);
}

// ---------------- fused prologue: token | weight-convert | init ------------
__global__ __launch_bounds__(256) void k_prep(
    const float* __restrict__ x, const float* __restrict__ nw,
    const float* __restrict__ rW,
    const float* __restrict__ w1, const float* __restrict__ w3,
    const float* __restrict__ w2,
    unsigned short* __restrict__ hid, int* __restrict__ t2i,
    float* __restrict__ t2g,
    unsigned short* __restrict__ d1, unsigned short* __restrict__ d3,
    unsigned short* __restrict__ d2,
    int* __restrict__ slot_token, int* __restrict__ meta)
{
    __shared__ float red[4];
    __shared__ float rl[4][8];
    int bid = blockIdx.x;
    int tid = threadIdx.x;

    if (bid >= PREP_CONV) {                  // ---- init ----
        int i = (bid - PREP_CONV) * 256 + tid;
        if (i < SLOTPAD) slot_token[i] = -1;
        if (i < 8) meta[i] = 0;
        return;
    }
    if (bid >= PREP_TOKEN) {                 // ---- weight convert ----
        size_t i = ((size_t)(bid - PREP_TOKEN) * 256 + tid) * 8;
        const float* s; unsigned short* d;
        if (i < (size_t)NWE)            { s = w1; d = d1; }
        else if (i < 2ull * NWE)        { s = w3; d = d3; i -= (size_t)NWE; }
        else                            { s = w2; d = d2; i -= 2ull * NWE; }
        float4 a = *(const float4*)(s + i);
        float4 b = *(const float4*)(s + i + 4);
        s16x8 v;
        v[0]=(short)f2bf(a.x); v[1]=(short)f2bf(a.y); v[2]=(short)f2bf(a.z); v[3]=(short)f2bf(a.w);
        v[4]=(short)f2bf(b.x); v[5]=(short)f2bf(b.y); v[6]=(short)f2bf(b.z); v[7]=(short)f2bf(b.w);
        *(s16x8*)(d + i) = v;
        return;
    }

    // ---- per-token: rmsnorm + rope (inline trig) + router ----
    int t = bid;
    int lane = tid & 63, wid = tid >> 6;
    int s = t & (Sm - 1);
    const float* xr = x + (size_t)t * Dm;

    float v0 = xr[tid], v1 = xr[tid + 256], v2 = xr[tid + 512], v3 = xr[tid + 768];
    float ss = v0*v0 + v1*v1 + v2*v2 + v3*v3;
    #pragma unroll
    for (int o = 32; o; o >>= 1) ss += __shfl_down(ss, o);
    if (lane == 0) red[wid] = ss;
    __syncthreads();
    float tot = red[0] + red[1] + red[2] + red[3];
    float rms = rsqrtf(tot * (1.0f / Dm) + 1e-6f);

    float n0 = v0 * rms * nw[tid];
    float n1 = v1 * rms * nw[tid + 256];
    float n2 = v2 * rms * nw[tid + 512];
    float n3 = v3 * rms * nw[tid + 768];

    // inv_freq = 10000^(-j/512) = exp(-j * ln(10000)/512)
    const float kk = -0.017988946039016842f;           // -ln(10000)/512
    float a0 = (float)s * expf((float)tid * kk);
    float a1 = (float)s * expf((float)(tid + 256) * kk);
    float c0x = cosf(a0), c0y = sinf(a0);
    float c1x = cosf(a1), c1y = sinf(a1);
    float h0 = n0 * c0x - n2 * c0y;
    float h2 = n0 * c0y + n2 * c0x;
    float h1 = n1 * c1x - n3 * c1y;
    float h3 = n1 * c1y + n3 * c1x;

    size_t base = (size_t)t * Dm;
    hid[base + tid]       = f2bf(h0);
    hid[base + tid + 256] = f2bf(h1);
    hid[base + tid + 512] = f2bf(h2);
    hid[base + tid + 768] = f2bf(h3);

    float p[8];
    #pragma unroll
    for (int e = 0; e < 8; e++) {
        const float* r = rW + (size_t)e * Dm;
        p[e] = h0 * r[tid] + h1 * r[tid + 256] + h2 * r[tid + 512] + h3 * r[tid + 768];
    }
    #pragma unroll
    for (int e = 0; e < 8; e++)
        #pragma unroll
        for (int o = 32; o; o >>= 1) p[e] += __shfl_down(p[e], o);
    if (lane == 0) {
        #pragma unroll
        for (int e = 0; e < 8; e++) rl[wid][e] = p[e];
    }
    __syncthreads();
    if (tid == 0) {
        float lg[8];
        #pragma unroll
        for (int e = 0; e < 8; e++) lg[e] = rl[0][e] + rl[1][e] + rl[2][e] + rl[3][e];
        float m = lg[0];
        #pragma unroll
        for (int e = 1; e < 8; e++) m = fmaxf(m, lg[e]);
        int i0 = 0; float b0 = lg[0];
        #pragma unroll
        for (int e = 1; e < 8; e++) if (lg[e] > b0) { b0 = lg[e]; i0 = e; }
        int i1 = -1; float b1 = -3.0e38f;
        #pragma unroll
        for (int e = 0; e < 8; e++) if (e != i0 && lg[e] > b1) { b1 = lg[e]; i1 = e; }
        float p0 = expf(b0 - m), p1 = expf(b1 - m);
        float inv = 1.0f / (p0 + p1);
        t2i[2 * t] = i0; t2i[2 * t + 1] = i1;
        t2g[2 * t] = p0 * inv; t2g[2 * t + 1] = p1 * inv;
    }
}

// ---------------- expert histogram: LDS-local then 8 atomics/block ----------
__global__ __launch_bounds__(256) void k_hist(const int* __restrict__ t2i,
                                              int* __restrict__ meta) {
    __shared__ int h[8];
    int tid = threadIdx.x;
    if (tid < 8) h[tid] = 0;
    __syncthreads();
    int base = blockIdx.x * 512 + tid * 2;   // 32 blocks cover 16384 entries
    atomicAdd(&h[t2i[base]], 1);
    atomicAdd(&h[t2i[base + 1]], 1);
    __syncthreads();
    if (tid < 8) atomicAdd(&meta[tid], h[tid]);
}

// ---------------- prefix offsets (padded to PADU=128) ----------------
__global__ void k_offsets(int* meta) {
    if (threadIdx.x == 0 && blockIdx.x == 0) {
        int acc = 0;
        for (int e = 0; e < 8; e++) {
            meta[8 + e] = acc;
            acc += ((meta[e] + PADU - 1) / PADU) * PADU;
        }
        meta[16] = acc;                       // padded_total
        for (int e = 0; e < 8; e++) meta[17 + e] = meta[8 + e]; // cursors
    }
}

// ---------------- slot placement: LDS rank + 8 cursor atomics/block --------
__global__ __launch_bounds__(256) void k_place(
    const int* __restrict__ t2i, const float* __restrict__ t2g,
    int* __restrict__ slot_token, float* __restrict__ slot_gate,
    int* __restrict__ t2s, int* __restrict__ meta)
{
    __shared__ int lcnt[8];
    __shared__ int lbase[8];
    int tid = threadIdx.x;
    if (tid < 8) lcnt[tid] = 0;
    __syncthreads();
    int t = blockIdx.x * 256 + tid;
    int e0 = t2i[2 * t], e1 = t2i[2 * t + 1];
    int r0 = atomicAdd(&lcnt[e0], 1);        // LDS atomics: per-CU, fast
    int r1 = atomicAdd(&lcnt[e1], 1);
    __syncthreads();
    if (tid < 8) lbase[tid] = atomicAdd(&meta[17 + tid], lcnt[tid]);
    __syncthreads();
    int p0 = lbase[e0] + r0, p1 = lbase[e1] + r1;
    slot_token[p0] = t; slot_gate[p0] = t2g[2 * t];     t2s[2 * t]     = p0;
    slot_token[p1] = t; slot_gate[p1] = t2g[2 * t + 1]; t2s[2 * t + 1] = p1;
}

// ---------------- GEMM1: act = silu(hid@w1^T) * (hid@w3^T) ----------------
// High-TLP config: 128 rows x 64 h-cols (dual G/U), BK=32, 256 threads,
// LDS 32 KB -> target 4 blocks/CU (16 waves/CU, 4/SIMD — 2x all prior cfgs).
// gemm2-style 2-phase counted-vmcnt pipeline: 4 glds/tile, vmcnt(4).
__global__ __launch_bounds__(256, 4) void k_gemm1(
    const unsigned short* __restrict__ hid,
    const unsigned short* __restrict__ w1b, const unsigned short* __restrict__ w3b,
    const int* __restrict__ slot_token, unsigned short* __restrict__ act,
    const int* __restrict__ meta)
{
    int nwg = gridDim.x * gridDim.y;
    int bid = blockIdx.y * gridDim.x + blockIdx.x;
    int wg  = xcd_swz(bid, nwg);
    int bx  = wg % gridDim.x, by = wg / gridDim.x;

    int row0 = by * 128;
    if (row0 >= meta[16]) return;
    int e = 0;
    #pragma unroll
    for (int q = 1; q < 8; q++) if (row0 >= meta[8 + q]) e = q;
    int h0 = bx * 64;

    __shared__ unsigned short As[2][128 * 32];   // rows 0-127 = slot rows
    __shared__ unsigned short Bs[2][128 * 32];   // rows 0-63 w1, 64-127 w3

    int tid = threadIdx.x, lane = tid & 63, w = tid >> 6;
    int wm = w >> 1, wn = w & 1;                 // wave: 64 rows x 32 cols dual
    int frow = lane & 15, q4 = lane >> 4;
    int rx = frow & 3;                           // read-side slot XOR (4 slots)

    // staging: granule g (64 rows); thread -> row g*64 + (tid>>2), seg tid&3
    int srow = tid >> 2;                         // 0..63
    int sslot = (tid & 3) ^ (srow & 3);          // pre-swizzled source k-slot

    const unsigned short* srcA[2];
    #pragma unroll
    for (int g = 0; g < 2; g++) {
        int tok = slot_token[row0 + g * 64 + srow];  if (tok < 0) tok = 0;
        srcA[g] = hid + (size_t)tok * Dm + sslot * 8;
    }
    const unsigned short* srcB0 = w1b + ((size_t)e * Hm + h0 + srow) * Dm + sslot * 8;
    const unsigned short* srcB1 = w3b + ((size_t)e * Hm + h0 + srow) * Dm + sslot * 8;

    f32x4 accG[4][2] = {};
    f32x4 accU[4][2] = {};

#define ST1(nb, k0) do {                                                      \
    gld16(srcA[0] + (k0), (unsigned short*)&As[(nb)][tid * 8]);               \
    gld16(srcA[1] + (k0), (unsigned short*)&As[(nb)][2048 + tid * 8]);        \
    gld16(srcB0   + (k0), (unsigned short*)&Bs[(nb)][tid * 8]);               \
    gld16(srcB1   + (k0), (unsigned short*)&Bs[(nb)][2048 + tid * 8]);        \
    } while (0)

#define CP1(buf) do {                                                         \
    int sp_ = q4 ^ rx;                                                        \
    s16x8 am_[4], bg_[2], bu_[2];                                             \
    _Pragma("unroll")                                                         \
    for (int i_ = 0; i_ < 4; i_++)                                            \
        am_[i_] = *(const s16x8*)&As[(buf)][(wm * 64 + i_ * 16 + frow) * 32 + sp_ * 8]; \
    _Pragma("unroll")                                                         \
    for (int j_ = 0; j_ < 2; j_++) {                                          \
        bg_[j_] = *(const s16x8*)&Bs[(buf)][(wn * 32 + j_ * 16 + frow) * 32 + sp_ * 8]; \
        bu_[j_] = *(const s16x8*)&Bs[(buf)][(64 + wn * 32 + j_ * 16 + frow) * 32 + sp_ * 8]; \
    }                                                                         \
    _Pragma("unroll")                                                         \
    for (int i_ = 0; i_ < 4; i_++)                                            \
        _Pragma("unroll")                                                     \
        for (int j_ = 0; j_ < 2; j_++) {                                      \
            accG[i_][j_] = mfma16(am_[i_], bg_[j_], accG[i_][j_]);            \
            accU[i_][j_] = mfma16(am_[i_], bu_[j_], accU[i_][j_]);            \
        }                                                                     \
    } while (0)

    ST1(0, 0);
    #pragma unroll 2
    for (int kt = 0; kt < 31; ++kt) {
        ST1((kt + 1) & 1, (kt + 1) * 32);
        asm volatile("s_waitcnt vmcnt(4)" ::: "memory");   // tile kt landed
        __builtin_amdgcn_s_barrier();
        __builtin_amdgcn_sched_barrier(0);
        CP1(kt & 1);
        __builtin_amdgcn_sched_barrier(0);
        __builtin_amdgcn_s_barrier();
    }
    asm volatile("s_waitcnt vmcnt(0)" ::: "memory");
    __builtin_amdgcn_s_barrier();
    __builtin_amdgcn_sched_barrier(0);
    CP1(1);

#undef ST1
#undef CP1

    #pragma unroll
    for (int i = 0; i < 4; i++)
        #pragma unroll
        for (int j = 0; j < 2; j++)
            #pragma unroll
            for (int r = 0; r < 4; r++) {
                int sr = row0 + wm * 64 + i * 16 + q4 * 4 + r;
                int hc = h0 + wn * 32 + j * 16 + frow;
                float g = accG[i][j][r], u = accU[i][j][r];
                float a = g / (1.0f + expf(-g)) * u;
                act[(size_t)sr * Hm + hc] = f2bf(a);
            }
}

// ---------------- GEMM2: sout[slot] = gate * (act @ w2^T), bf16 ----------------
// 128 rows x 128 D-cols per block; BK=64; 2-deep counted-vmcnt pipeline.
__global__ __launch_bounds__(256) void k_gemm2(
    const unsigned short* __restrict__ act, const unsigned short* __restrict__ w2b,
    const float* __restrict__ slot_gate,
    unsigned short* __restrict__ sout, const int* __restrict__ meta)
{
    int nwg = gridDim.x * gridDim.y;
    int bid = blockIdx.y * gridDim.x + blockIdx.x;
    int wg  = xcd_swz(bid, nwg);
    int bx  = wg % gridDim.x, by = wg / gridDim.x;

    int row0 = by * 128;
    if (row0 >= meta[16]) return;
    int e = 0;
    #pragma unroll
    for (int q = 1; q < 8; q++) if (row0 >= meta[8 + q]) e = q;
    int d0 = bx * 128;

    __shared__ unsigned short As[2][128 * 64];
    __shared__ unsigned short Bs[2][128 * 64];
    __shared__ float sgat[128];

    int tid = threadIdx.x, lane = tid & 63, w = tid >> 6;
    int wm = w >> 1, wn = w & 1;
    int frow = lane & 15, q4 = lane >> 4;
    int rx = frow & 7;

    if (tid < 128) sgat[tid] = slot_gate[row0 + tid];

    int r7 = (tid >> 3) & 7;
    int sslot = (tid & 7) ^ r7;

    const unsigned short* srcA[4];
    const unsigned short* srcB[4];
    #pragma unroll
    for (int i = 0; i < 4; i++) {
        int rr = i * 32 + (tid >> 3);
        srcA[i] = act + (size_t)(row0 + rr) * Hm + sslot * 8;
        srcB[i] = w2b + ((size_t)e * Dm + d0 + rr) * Hm + sslot * 8;
    }

    f32x4 acc[4][4] = {};

#define STAGE2(buf, k0) do {                                                  \
    unsigned short* la_ = &As[(buf)][tid * 8];                                \
    unsigned short* lb_ = &Bs[(buf)][tid * 8];                                \
    _Pragma("unroll")                                                         \
    for (int i_ = 0; i_ < 4; i_++) {                                          \
        gld16(srcA[i_] + (k0), la_ + i_ * 2048);                              \
        gld16(srcB[i_] + (k0), lb_ + i_ * 2048);                              \
    } } while (0)

#define COMP2(buf) do {                                                       \
    _Pragma("unroll")                                                         \
    for (int h_ = 0; h_ < 2; h_++) {                                          \
        int sp_ = ((h_ << 2) | q4) ^ rx;                                      \
        s16x8 am_[4], bn_[4];                                                 \
        _Pragma("unroll")                                                     \
        for (int i_ = 0; i_ < 4; i_++)                                        \
            am_[i_] = *(const s16x8*)&As[(buf)][(wm * 64 + i_ * 16 + frow) * 64 + sp_ * 8]; \
        _Pragma("unroll")                                                     \
        for (int j_ = 0; j_ < 4; j_++)                                        \
            bn_[j_] = *(const s16x8*)&Bs[(buf)][(wn * 64 + j_ * 16 + frow) * 64 + sp_ * 8]; \
        _Pragma("unroll")                                                     \
        for (int i_ = 0; i_ < 4; i_++)                                        \
            _Pragma("unroll")                                                 \
            for (int j_ = 0; j_ < 4; j_++)                                    \
                acc[i_][j_] = mfma16(am_[i_], bn_[j_], acc[i_][j_]);          \
    } } while (0)

    STAGE2(0, 0);
    #pragma unroll 2
    for (int kt = 0; kt < 31; ++kt) {
        STAGE2((kt + 1) & 1, (kt + 1) * 64);
        asm volatile("s_waitcnt vmcnt(8)" ::: "memory");
        __builtin_amdgcn_s_barrier();
        __builtin_amdgcn_sched_barrier(0);
        COMP2(kt & 1);
        __builtin_amdgcn_sched_barrier(0);
        __builtin_amdgcn_s_barrier();
    }
    asm volatile("s_waitcnt vmcnt(0)" ::: "memory");
    __builtin_amdgcn_s_barrier();
    __builtin_amdgcn_sched_barrier(0);
    COMP2(1);

#undef STAGE2
#undef COMP2

    #pragma unroll
    for (int i = 0; i < 4; i++) {
        #pragma unroll
        for (int r = 0; r < 4; r++) {
            int srl = wm * 64 + i * 16 + q4 * 4 + r;
            float gate = sgat[srl];
            size_t rb = (size_t)(row0 + srl) * Dm;
            #pragma unroll
            for (int j = 0; j < 4; j++) {
                int dc = d0 + wn * 64 + j * 16 + frow;
                sout[rb + dc] = f2bf(gate * acc[i][j][r]);
            }
        }
    }
}

// ---------------- final gather: out = x + sout[s0] + sout[s1] ----------------
__global__ __launch_bounds__(256) void k_final(
    const float* __restrict__ x, const unsigned short* __restrict__ sout,
    const int* __restrict__ t2s, float* __restrict__ out)
{
    int t = blockIdx.x;
    int tid = threadIdx.x;
    int s0 = t2s[2 * t], s1 = t2s[2 * t + 1];
    const float4*  xr = (const float4*)(x + (size_t)t * Dm);
    const ushort4* a  = (const ushort4*)(sout + (size_t)s0 * Dm);
    const ushort4* b  = (const ushort4*)(sout + (size_t)s1 * Dm);
    float4* o = (float4*)(out + (size_t)t * Dm);
    float4 xv = xr[tid];
    ushort4 av = a[tid], bv = b[tid];
    float4 r;
    r.x = xv.x + bf2f(av.x) + bf2f(bv.x);
    r.y = xv.y + bf2f(av.y) + bf2f(bv.y);
    r.z = xv.z + bf2f(av.z) + bf2f(bv.z);
    r.w = xv.w + bf2f(av.w) + bf2f(bv.w);
    o[tid] = r;
}

extern "C" void kernel_launch(void* const* d_in, const int* in_sizes, int n_in,
                              void* d_out, int out_size, void* d_ws, size_t ws_size,
                              hipStream_t stream) {
    const float* x  = (const float*)d_in[0];
    const float* nw = (const float*)d_in[1];
    const float* rW = (const float*)d_in[2];
    const float* w1 = (const float*)d_in[3];
    const float* w3 = (const float*)d_in[4];
    const float* w2 = (const float*)d_in[5];
    float* out = (float*)d_out;
    char* ws = (char*)d_ws;

    unsigned short* hid = (unsigned short*)(ws + OF_HID);
    unsigned short* act = (unsigned short*)(ws + OF_ACT);
    unsigned short* w1b = (unsigned short*)(ws + OF_W1B);
    unsigned short* w3b = (unsigned short*)(ws + OF_W3B);
    unsigned short* w2b = (unsigned short*)(ws + OF_W2B);
    int*   t2i  = (int*)(ws + OF_T2I);
    float* t2g  = (float*)(ws + OF_T2G);
    int*   t2s  = (int*)(ws + OF_T2S);
    int*   stok = (int*)(ws + OF_ST);
    float* sgat = (float*)(ws + OF_SG);
    int*   meta = (int*)(ws + OF_MT);
    unsigned short* sout = (unsigned short*)(ws + OF_SO);

    k_prep<<<PREP_INIT, 256, 0, stream>>>(x, nw, rW, w1, w3, w2,
                                          hid, t2i, t2g, w1b, w3b, w2b,
                                          stok, meta);
    k_hist<<<32, 256, 0, stream>>>(t2i, meta);
    k_offsets<<<1, 64, 0, stream>>>(meta);
    k_place<<<TOKENS / 256, 256, 0, stream>>>(t2i, t2g, stok, sgat, t2s, meta);

    dim3 g1(Hm / 64, SLOTPAD / 128);         // 32 x 136 = 4352 blocks
    k_gemm1<<<g1, 256, 0, stream>>>(hid, w1b, w3b, stok, act, meta);
    dim3 g2(Dm / 128, SLOTPAD / 128);        // 8 x 136 = 1088 blocks
    k_gemm2<<<g2, 256, 0, stream>>>(act, w2b, sgat, sout, meta);
    k_final<<<TOKENS, 256, 0, stream>>>(x, sout, t2s, out);
}